// Round 5
// baseline (5045.795 us; speedup 1.0000x reference)
//
#include <hip/hip_runtime.h>

typedef unsigned int u32;
typedef unsigned short u16;
typedef __attribute__((ext_vector_type(8))) short short8;
typedef __attribute__((ext_vector_type(4))) float f32x4;

#define CBSZ 8192
#define DIMV 512
#define MROWS 32768   // 8*4096
#define CAP 24
#define DELTA 0.125f

__device__ __forceinline__ u16 f2bf(float f) {
    u32 u = __float_as_uint(f);
    u32 r = (u + 0x7fffu + ((u >> 16) & 1u)) >> 16;   // RNE
    return (u16)r;
}

__device__ __forceinline__ float wave_sum(float v) {
#pragma unroll
    for (int m = 1; m < 64; m <<= 1) v += __shfl_xor(v, m);
    return v;
}

// monotone float <-> sortable u32
__device__ __forceinline__ u32 enc_f(float f) {
    u32 u = __float_as_uint(f);
    return (u & 0x80000000u) ? ~u : (u | 0x80000000u);
}
__device__ __forceinline__ float dec_f(u32 e) {
    return (e & 0x80000000u) ? __uint_as_float(e & 0x7FFFFFFFu) : __uint_as_float(~e);
}

// async global->LDS, 16B per lane; LDS dest = wave-uniform base + lane*16
__device__ __forceinline__ void gl_lds16(const u16* g, u16* l) {
    __builtin_amdgcn_global_load_lds(
        (const __attribute__((address_space(1))) u32*)g,
        (__attribute__((address_space(3))) u32*)l, 16, 0, 0);
}

// K0: cast x (f32) -> xb (bf16) in MFMA-A-fragment-linear order.
// frag f = R*16 + S (R=row-tile of 16, S=k-tile of 32); within frag, lane L
// holds row R*16+(L&15), k S*32+(L>>4)*8, 8 bf16 = 16B at f*1024 + L*16.
__global__ __launch_bounds__(256) void k0_castx(const float* __restrict__ x,
                                                u16* __restrict__ xb) {
    int t = blockIdx.x * 256 + threadIdx.x;   // 0 .. 2,097,151
    int f = t >> 6;
    int L = t & 63;
    int R = f >> 4, S = f & 15;
    int row = R * 16 + (L & 15);
    int k = S * 32 + (L >> 4) * 8;
    const float* gp = x + (size_t)row * DIMV + k;
    float4 v0 = *(const float4*)gp, v1 = *(const float4*)(gp + 4);
    u32 p0 = (u32)f2bf(v0.x) | ((u32)f2bf(v0.y) << 16);
    u32 p1 = (u32)f2bf(v0.z) | ((u32)f2bf(v0.w) << 16);
    u32 p2 = (u32)f2bf(v1.x) | ((u32)f2bf(v1.y) << 16);
    u32 p3 = (u32)f2bf(v1.z) | ((u32)f2bf(v1.w) << 16);
    *(uint4*)(xb + (size_t)f * 512 + L * 8) = make_uint4(p0, p1, p2, p3);
}

// K1: implicit_cb[c][d] = sum_k cb[c][k] * W[d][k]   (fp32 GEMM, 64x64 tiles)
__global__ __launch_bounds__(256) void k1_implicit(const float* __restrict__ cb,
                                                   const float* __restrict__ W,
                                                   float* __restrict__ outp) {
    __shared__ float As[64 * 64];
    __shared__ float Bs[64 * 64];
    const int c0 = blockIdx.x * 64, d0 = blockIdx.y * 64;
    const int tid = threadIdx.x;
    const int tx = tid & 15, ty = tid >> 4;
    float acc[4][4] = {};
    for (int k0 = 0; k0 < DIMV; k0 += 64) {
        __syncthreads();
#pragma unroll
        for (int it = 0; it < 4; ++it) {
            int chunk = tid + 256 * it;
            int row = chunk >> 4;
            int g = chunk & 15;
            int gs = (g ^ (row & 15)) * 4;
            *(float4*)&As[row * 64 + gs] =
                *(const float4*)(cb + (size_t)(c0 + row) * DIMV + k0 + g * 4);
            *(float4*)&Bs[row * 64 + gs] =
                *(const float4*)(W + (size_t)(d0 + row) * DIMV + k0 + g * 4);
        }
        __syncthreads();
#pragma unroll
        for (int k = 0; k < 64; k += 4) {
            const int g = k >> 2;
            float4 a[4], b[4];
#pragma unroll
            for (int i = 0; i < 4; ++i) a[i] = *(float4*)&As[(ty + 16 * i) * 64 + ((g ^ ty) * 4)];
#pragma unroll
            for (int j = 0; j < 4; ++j) b[j] = *(float4*)&Bs[(tx + 16 * j) * 64 + ((g ^ tx) * 4)];
#pragma unroll
            for (int i = 0; i < 4; ++i)
#pragma unroll
                for (int j = 0; j < 4; ++j) {
                    acc[i][j] = fmaf(a[i].x, b[j].x, acc[i][j]);
                    acc[i][j] = fmaf(a[i].y, b[j].y, acc[i][j]);
                    acc[i][j] = fmaf(a[i].z, b[j].z, acc[i][j]);
                    acc[i][j] = fmaf(a[i].w, b[j].w, acc[i][j]);
                }
        }
    }
#pragma unroll
    for (int i = 0; i < 4; ++i)
#pragma unroll
        for (int j = 0; j < 4; ++j)
            outp[(size_t)(c0 + ty + 16 * i) * DIMV + d0 + tx + 16 * j] = acc[i][j];
}

// K2: in-place row l2norm of cbn + write bf16 codebook in B-fragment-linear order.
__global__ __launch_bounds__(256) void k2_normrows(float* __restrict__ cbn,
                                                   u16* __restrict__ cbb) {
    const int row = blockIdx.x * 4 + (threadIdx.x >> 6);
    const int lane = threadIdx.x & 63;
    float* p = cbn + (size_t)row * DIMV + lane * 8;
    float4 v0 = *(float4*)p, v1 = *(float4*)(p + 4);
    float ss = v0.x * v0.x + v0.y * v0.y + v0.z * v0.z + v0.w * v0.w
             + v1.x * v1.x + v1.y * v1.y + v1.z * v1.z + v1.w * v1.w;
    ss = wave_sum(ss);
    float n = fmaxf(sqrtf(ss), 1e-12f);
    v0.x /= n; v0.y /= n; v0.z /= n; v0.w /= n;
    v1.x /= n; v1.y /= n; v1.z /= n; v1.w /= n;
    *(float4*)p = v0;
    *(float4*)(p + 4) = v1;
    u32 p0 = (u32)f2bf(v0.x) | ((u32)f2bf(v0.y) << 16);
    u32 p1 = (u32)f2bf(v0.z) | ((u32)f2bf(v0.w) << 16);
    u32 p2 = (u32)f2bf(v1.x) | ((u32)f2bf(v1.y) << 16);
    u32 p3 = (u32)f2bf(v1.z) | ((u32)f2bf(v1.w) << 16);
    // frag-linear: f = (row>>4)*16 + (lane>>2); lane-slot = (lane&3)*16 + (row&15)
    int f = (row >> 4) * 16 + (lane >> 2);
    int Ls = (lane & 3) * 16 + (row & 15);
    *(uint4*)(cbb + (size_t)f * 512 + Ls * 8) = make_uint4(p0, p1, p2, p3);
}

// K3: bf16 MFMA prefilter. Grid (256 row-blocks, 2 code-halves), 512 threads.
// Block = 128 rows x 4096 codes (chunks of 128). Staging via global_load_lds
// from fragment-linear xb/cbb (1KB contiguous per instruction per wave).
// Per-row prefix max (ordered-u32 atomicMax) + candidates within DELTA.
__global__ __launch_bounds__(512, 4) void k3_scan(const u16* __restrict__ xb,
                                                  const u16* __restrict__ cbb,
                                                  u16* __restrict__ cand_g,
                                                  u32* __restrict__ cnt_g) {
    __shared__ __align__(16) u16 xs[32 * 512];    // 32 KB: 8 row-tiles x 4 k-tiles
    __shared__ __align__(16) u16 cbs[32 * 512];   // 32 KB: 8 code-tiles x 4 k-tiles
    __shared__ u32 pmax[128];
    __shared__ u32 cnt[128];
    __shared__ u16 cand[128 * CAP];

    const int tid = threadIdx.x;
    const int lane = tid & 63;
    const int w = tid >> 6;                  // wave 0..7
    const int w_r = w >> 1, w_c = w & 1;     // 4 row-groups x 2 code-groups
    const int r0 = blockIdx.x * 128;
    const int r0t = blockIdx.x * 8;          // row-tile base
    const int h = blockIdx.y;                // code half
    const int cb0 = h * (CBSZ / 2);

    if (tid < 128) { pmax[tid] = 0x007FFFFFu; cnt[tid] = 0; }   // enc(-inf), 0
    __syncthreads();

    for (int ct = 0; ct < CBSZ / 2; ct += 128) {
        f32x4 acc[2][4] = {};
        const int ctile = (cb0 + ct) >> 4;
        for (int kc = 0; kc < 4; ++kc) {
            __syncthreads();                 // prior reads done before overwrite
            // each wave stages 4 xs frags + 4 cbs frags (1KB each, contiguous)
#pragma unroll
            for (int i = 0; i < 4; ++i) {
                int m = w * 4 + i;           // 0..31
                int rt = m >> 2, s = m & 3;
                int fx = (r0t + rt) * 16 + kc * 4 + s;
                gl_lds16(xb + (size_t)fx * 512 + lane * 8, &xs[m * 512]);
                int fc = (ctile + rt) * 16 + kc * 4 + s;
                gl_lds16(cbb + (size_t)fc * 512 + lane * 8, &cbs[m * 512]);
            }
            __syncthreads();                 // waits vmcnt(0): staging complete
#pragma unroll
            for (int s = 0; s < 4; ++s) {
                short8 a[2], b[4];
#pragma unroll
                for (int t = 0; t < 2; ++t)
                    a[t] = *(const short8*)&xs[((w_r * 2 + t) * 4 + s) * 512 + lane * 8];
#pragma unroll
                for (int u = 0; u < 4; ++u)
                    b[u] = *(const short8*)&cbs[((w_c * 4 + u) * 4 + s) * 512 + lane * 8];
#pragma unroll
                for (int t = 0; t < 2; ++t)
#pragma unroll
                    for (int u = 0; u < 4; ++u)
                        acc[t][u] = __builtin_amdgcn_mfma_f32_16x16x32_bf16(a[t], b[u], acc[t][u], 0, 0, 0);
            }
        }
        // --- candidate phase ---
#pragma unroll
        for (int t = 0; t < 2; ++t)
#pragma unroll
            for (int r = 0; r < 4; ++r) {
                float m = fmaxf(fmaxf(acc[t][0][r], acc[t][1][r]),
                                fmaxf(acc[t][2][r], acc[t][3][r]));
#pragma unroll
                for (int msk = 1; msk < 16; msk <<= 1) m = fmaxf(m, __shfl_xor(m, msk));
                if ((lane & 15) == 0) {
                    int rl = (w_r * 2 + t) * 16 + (lane >> 4) * 4 + r;
                    atomicMax(&pmax[rl], enc_f(m));
                }
            }
        __syncthreads();
#pragma unroll
        for (int t = 0; t < 2; ++t)
#pragma unroll
            for (int r = 0; r < 4; ++r) {
                int rl = (w_r * 2 + t) * 16 + (lane >> 4) * 4 + r;
                float thr = dec_f(pmax[rl]) - DELTA;
#pragma unroll
                for (int u = 0; u < 4; ++u) {
                    if (acc[t][u][r] >= thr) {
                        u32 p = atomicAdd(&cnt[rl], 1u);
                        int code = cb0 + ct + w_c * 64 + u * 16 + (lane & 15);
                        if (p < CAP) cand[rl * CAP + p] = (u16)code;
                    }
                }
            }
        // next chunk's first barrier orders pushes before next pmax updates
    }
    __syncthreads();
    if (tid < 128) cnt_g[(size_t)(r0 + tid) * 2 + h] = cnt[tid];
    for (int i = tid; i < 128 * CAP; i += 512) {
        int row = i / CAP, j = i - row * CAP;
        cand_g[((size_t)(r0 + row) * 2 + h) * CAP + j] = cand[i];
    }
}

// K4: fp64 rescore of the two halves' candidates + gather + rotation trick +
// commit-loss partial. One wave per row.
__global__ __launch_bounds__(256) void k4_rotate(const float* __restrict__ x,
                                                 const float* __restrict__ cbn,
                                                 const u16* __restrict__ cand_g,
                                                 const u32* __restrict__ cnt_g,
                                                 float* __restrict__ outq,
                                                 float* __restrict__ out_idx,
                                                 float* __restrict__ lossp) {
    const int row = blockIdx.x * 4 + (threadIdx.x >> 6);
    const int lane = threadIdx.x & 63;
    const float* xp = x + (size_t)row * DIMV + lane * 8;
    float4 a0 = *(const float4*)xp, a1 = *(const float4*)(xp + 4);
    double xd[8] = {a0.x, a0.y, a0.z, a0.w, a1.x, a1.y, a1.z, a1.w};

    u32 n0 = cnt_g[(size_t)row * 2], n1 = cnt_g[(size_t)row * 2 + 1];
    double best = -1e300;
    int bi = CBSZ;
    if (n0 <= CAP && n1 <= CAP) {
        for (int hh = 0; hh < 2; ++hh) {
            u32 nc = hh ? n1 : n0;
            for (u32 i = 0; i < nc; ++i) {
                int c = cand_g[((size_t)row * 2 + hh) * CAP + i];
                const float* cp = cbn + (size_t)c * DIMV + lane * 8;
                float4 c0 = *(const float4*)cp, c1 = *(const float4*)(cp + 4);
                double d = xd[0] * c0.x + xd[1] * c0.y + xd[2] * c0.z + xd[3] * c0.w
                         + xd[4] * c1.x + xd[5] * c1.y + xd[6] * c1.z + xd[7] * c1.w;
#pragma unroll
                for (int m = 1; m < 64; m <<= 1) d += __shfl_xor(d, m);
                if (d > best || (d == best && c < bi)) { best = d; bi = c; }
            }
        }
    } else {
        // overflow fallback (statistically never): exact fp64 full scan
        for (int c = 0; c < CBSZ; ++c) {
            const float* cp = cbn + (size_t)c * DIMV + lane * 8;
            float4 c0 = *(const float4*)cp, c1 = *(const float4*)(cp + 4);
            double d = xd[0] * c0.x + xd[1] * c0.y + xd[2] * c0.z + xd[3] * c0.w
                     + xd[4] * c1.x + xd[5] * c1.y + xd[6] * c1.z + xd[7] * c1.w;
#pragma unroll
            for (int m = 1; m < 64; m <<= 1) d += __shfl_xor(d, m);
            if (d > best || (d == best && c < bi)) { best = d; bi = c; }
        }
    }
    int ci = bi < 0 ? 0 : (bi > CBSZ - 1 ? CBSZ - 1 : bi);

    float xf[8] = {a0.x, a0.y, a0.z, a0.w, a1.x, a1.y, a1.z, a1.w};
    float ss = 0.f;
#pragma unroll
    for (int i = 0; i < 8; ++i) ss += xf[i] * xf[i];
    ss = wave_sum(ss);
    float nx = fmaxf(sqrtf(ss), 1e-12f);
    float s[8];
#pragma unroll
    for (int i = 0; i < 8; ++i) s[i] = xf[i] / nx;
    const float* tp = cbn + (size_t)ci * DIMV + lane * 8;
    float4 t0 = *(const float4*)tp, t1 = *(const float4*)(tp + 4);
    float t[8] = {t0.x, t0.y, t0.z, t0.w, t1.x, t1.y, t1.z, t1.w};
    float ns2 = 0.f, nt2 = 0.f;
#pragma unroll
    for (int i = 0; i < 8; ++i) { ns2 += s[i] * s[i]; nt2 += t[i] * t[i]; }
    ns2 = wave_sum(ns2); nt2 = wave_sum(nt2);
    float ns = sqrtf(ns2), nt = sqrtf(nt2);
    float ds = fmaxf(ns, 1e-6f), dt = fmaxf(nt, 1e-6f);
    float uu[8], qq[8], wv[8];
#pragma unroll
    for (int i = 0; i < 8; ++i) { uu[i] = s[i] / ds; qq[i] = t[i] / dt; wv[i] = uu[i] + qq[i]; }
    float w2 = 0.f;
#pragma unroll
    for (int i = 0; i < 8; ++i) w2 += wv[i] * wv[i];
    w2 = wave_sum(w2);
    float wn = fmaxf(sqrtf(w2), 1e-12f);
#pragma unroll
    for (int i = 0; i < 8; ++i) wv[i] /= wn;
    float ew = 0.f, eu = 0.f;
#pragma unroll
    for (int i = 0; i < 8; ++i) { ew += s[i] * wv[i]; eu += s[i] * uu[i]; }
    ew = wave_sum(ew); eu = wave_sum(eu);
    const float scale = nt / ds;
    float r[8];
    float lacc = 0.f;
#pragma unroll
    for (int i = 0; i < 8; ++i) {
        r[i] = (s[i] - 2.f * ew * wv[i] + 2.f * eu * qq[i]) * scale;
        float d = s[i] - t[i];
        lacc += d * d;
    }
    float* op = outq + (size_t)row * DIMV + lane * 8;
    *(float4*)op = make_float4(r[0], r[1], r[2], r[3]);
    *(float4*)(op + 4) = make_float4(r[4], r[5], r[6], r[7]);
    lacc = wave_sum(lacc);
    if (lane == 0) {
        out_idx[row] = (float)ci;
        atomicAdd(lossp, lacc);
    }
}

// K5: finalize: 1.25 * sum / (B*N*D)
__global__ void k5_loss(const float* __restrict__ lossp, float* __restrict__ outl) {
    outl[0] = lossp[0] * 1.25f / 16777216.0f;
}

extern "C" void kernel_launch(void* const* d_in, const int* in_sizes, int n_in,
                              void* d_out, int out_size, void* d_ws, size_t ws_size,
                              hipStream_t stream) {
    (void)in_sizes; (void)n_in; (void)out_size; (void)ws_size;
    const float* x  = (const float*)d_in[0];   // (8,4096,512) f32
    const float* W  = (const float*)d_in[1];   // (512,512) f32
    const float* cb = (const float*)d_in[2];   // (8192,512) f32
    float* out = (float*)d_out;
    float* out_q = out;                        // 16,777,216 f32
    float* out_i = out + 16777216;             // 32,768 f32
    float* out_l = out + 16777216 + 32768;     // 1 f32

    // xb scratch lives in the out_q region (33.5 MB < 64 MB): written by k0,
    // read only by k3, then k4 overwrites out_q with the real output.
    u16* xb = (u16*)d_out;

    float* ws = (float*)d_ws;
    float* cbn = ws;                                  // 4,194,304 f32 (16.8 MB)
    u16*   cbb = (u16*)(cbn + (size_t)CBSZ * DIMV);   // 4,194,304 u16 (8.4 MB)
    u16*   cand_g = cbb + (size_t)CBSZ * DIMV;        // 32768*2*CAP u16 (3.1 MB)
    u32*   cnt_g = (u32*)(cand_g + (size_t)MROWS * 2 * CAP);   // 65,536 u32
    float* lossp = (float*)(cnt_g + (size_t)MROWS * 2);        // 1 f32

    hipMemsetAsync(lossp, 0, sizeof(float), stream);
    k0_castx<<<MROWS * DIMV / 8 / 256, 256, 0, stream>>>(x, xb);
    k1_implicit<<<dim3(CBSZ / 64, DIMV / 64), 256, 0, stream>>>(cb, W, cbn);
    k2_normrows<<<CBSZ / 4, 256, 0, stream>>>(cbn, cbb);
    k3_scan<<<dim3(MROWS / 128, 2), 512, 0, stream>>>(xb, cbb, cand_g, cnt_g);
    k4_rotate<<<MROWS / 4, 256, 0, stream>>>(x, cbn, cand_g, cnt_g, out_q, out_i, lossp);
    k5_loss<<<1, 1, 0, stream>>>(lossp, out_l);
}

// Round 6
// 932.296 us; speedup vs baseline: 5.4122x; 5.4122x over previous
//
#include <hip/hip_runtime.h>

typedef unsigned int u32;
typedef unsigned short u16;
typedef __attribute__((ext_vector_type(8))) short short8;
typedef __attribute__((ext_vector_type(4))) float f32x4;

#define CBSZ 8192
#define DIMV 512
#define MROWS 32768   // 8*4096
#define CAP 48
#define DELTA 0.125f

__device__ __forceinline__ u16 f2bf(float f) {
    u32 u = __float_as_uint(f);
    u32 r = (u + 0x7fffu + ((u >> 16) & 1u)) >> 16;   // RNE
    return (u16)r;
}

__device__ __forceinline__ float wave_sum(float v) {
#pragma unroll
    for (int m = 1; m < 64; m <<= 1) v += __shfl_xor(v, m);
    return v;
}

// monotone float <-> sortable u32
__device__ __forceinline__ u32 enc_f(float f) {
    u32 u = __float_as_uint(f);
    return (u & 0x80000000u) ? ~u : (u | 0x80000000u);
}
__device__ __forceinline__ float dec_f(u32 e) {
    return (e & 0x80000000u) ? __uint_as_float(e & 0x7FFFFFFFu) : __uint_as_float(~e);
}

// async global->LDS, 16B per lane; LDS dest = wave-uniform base + lane*16
__device__ __forceinline__ void gl_lds16(const u16* g, u16* l) {
    __builtin_amdgcn_global_load_lds(
        (const __attribute__((address_space(1))) u32*)g,
        (__attribute__((address_space(3))) u32*)l, 16, 0, 0);
}

// K0: cast x (f32) -> xb (bf16) in MFMA-A-fragment-linear order.
// frag f = R*16 + S (R=row-tile/16, S=k-tile/32); lane L holds row R*16+(L&15),
// k S*32+(L>>4)*8 .. +8, stored as 16B at xb + f*512 + L*8 (u16 elems).
__global__ __launch_bounds__(256) void k0_castx(const float* __restrict__ x,
                                                u16* __restrict__ xb) {
    int t = blockIdx.x * 256 + threadIdx.x;   // 0 .. 2,097,151
    int f = t >> 6;
    int L = t & 63;
    int R = f >> 4, S = f & 15;
    int row = R * 16 + (L & 15);
    int k = S * 32 + (L >> 4) * 8;
    const float* gp = x + (size_t)row * DIMV + k;
    float4 v0 = *(const float4*)gp, v1 = *(const float4*)(gp + 4);
    u32 p0 = (u32)f2bf(v0.x) | ((u32)f2bf(v0.y) << 16);
    u32 p1 = (u32)f2bf(v0.z) | ((u32)f2bf(v0.w) << 16);
    u32 p2 = (u32)f2bf(v1.x) | ((u32)f2bf(v1.y) << 16);
    u32 p3 = (u32)f2bf(v1.z) | ((u32)f2bf(v1.w) << 16);
    *(uint4*)(xb + (size_t)f * 512 + L * 8) = make_uint4(p0, p1, p2, p3);
}

// K1: implicit_cb[c][d] = sum_k cb[c][k] * W[d][k]   (fp32 GEMM, 64x64 tiles)
__global__ __launch_bounds__(256) void k1_implicit(const float* __restrict__ cb,
                                                   const float* __restrict__ W,
                                                   float* __restrict__ outp) {
    __shared__ float As[64 * 64];
    __shared__ float Bs[64 * 64];
    const int c0 = blockIdx.x * 64, d0 = blockIdx.y * 64;
    const int tid = threadIdx.x;
    const int tx = tid & 15, ty = tid >> 4;
    float acc[4][4] = {};
    for (int k0 = 0; k0 < DIMV; k0 += 64) {
        __syncthreads();
#pragma unroll
        for (int it = 0; it < 4; ++it) {
            int chunk = tid + 256 * it;
            int row = chunk >> 4;
            int g = chunk & 15;
            int gs = (g ^ (row & 15)) * 4;
            *(float4*)&As[row * 64 + gs] =
                *(const float4*)(cb + (size_t)(c0 + row) * DIMV + k0 + g * 4);
            *(float4*)&Bs[row * 64 + gs] =
                *(const float4*)(W + (size_t)(d0 + row) * DIMV + k0 + g * 4);
        }
        __syncthreads();
#pragma unroll
        for (int k = 0; k < 64; k += 4) {
            const int g = k >> 2;
            float4 a[4], b[4];
#pragma unroll
            for (int i = 0; i < 4; ++i) a[i] = *(float4*)&As[(ty + 16 * i) * 64 + ((g ^ ty) * 4)];
#pragma unroll
            for (int j = 0; j < 4; ++j) b[j] = *(float4*)&Bs[(tx + 16 * j) * 64 + ((g ^ tx) * 4)];
#pragma unroll
            for (int i = 0; i < 4; ++i)
#pragma unroll
                for (int j = 0; j < 4; ++j) {
                    acc[i][j] = fmaf(a[i].x, b[j].x, acc[i][j]);
                    acc[i][j] = fmaf(a[i].y, b[j].y, acc[i][j]);
                    acc[i][j] = fmaf(a[i].z, b[j].z, acc[i][j]);
                    acc[i][j] = fmaf(a[i].w, b[j].w, acc[i][j]);
                }
        }
    }
#pragma unroll
    for (int i = 0; i < 4; ++i)
#pragma unroll
        for (int j = 0; j < 4; ++j)
            outp[(size_t)(c0 + ty + 16 * i) * DIMV + d0 + tx + 16 * j] = acc[i][j];
}

// K2: in-place row l2norm of cbn + bf16 codebook in B-fragment-linear order.
__global__ __launch_bounds__(256) void k2_normrows(float* __restrict__ cbn,
                                                   u16* __restrict__ cbb) {
    const int row = blockIdx.x * 4 + (threadIdx.x >> 6);
    const int lane = threadIdx.x & 63;
    float* p = cbn + (size_t)row * DIMV + lane * 8;
    float4 v0 = *(float4*)p, v1 = *(float4*)(p + 4);
    float ss = v0.x * v0.x + v0.y * v0.y + v0.z * v0.z + v0.w * v0.w
             + v1.x * v1.x + v1.y * v1.y + v1.z * v1.z + v1.w * v1.w;
    ss = wave_sum(ss);
    float n = fmaxf(sqrtf(ss), 1e-12f);
    v0.x /= n; v0.y /= n; v0.z /= n; v0.w /= n;
    v1.x /= n; v1.y /= n; v1.z /= n; v1.w /= n;
    *(float4*)p = v0;
    *(float4*)(p + 4) = v1;
    u32 p0 = (u32)f2bf(v0.x) | ((u32)f2bf(v0.y) << 16);
    u32 p1 = (u32)f2bf(v0.z) | ((u32)f2bf(v0.w) << 16);
    u32 p2 = (u32)f2bf(v1.x) | ((u32)f2bf(v1.y) << 16);
    u32 p3 = (u32)f2bf(v1.z) | ((u32)f2bf(v1.w) << 16);
    // B-frag-linear: f = (row>>4)*16 + (lane>>2); lane-slot = (lane&3)*16 + (row&15)
    int f = (row >> 4) * 16 + (lane >> 2);
    int Ls = (lane & 3) * 16 + (row & 15);
    *(uint4*)(cbb + (size_t)f * 512 + Ls * 8) = make_uint4(p0, p1, p2, p3);
}

// K3: barrier-free bf16 MFMA prefilter. Grid 512 blocks x 512 thr (8 waves).
// Block = 64 rows (xs resident, 64KB LDS) x all 8192 codes; wave w streams its
// code tiles straight from global (frag-linear cbb) into registers.
// Per-row prefix max in LDS (atomicMax, lag-safe) + candidates within DELTA.
__global__ __launch_bounds__(512, 4) void k3_scan(const u16* __restrict__ xb,
                                                  const u16* __restrict__ cbb,
                                                  u16* __restrict__ cand_g,
                                                  u32* __restrict__ cnt_g) {
    __shared__ __align__(16) u16 xs[64 * 512];   // 64 KB: frag m=rt*16+kf at m*512
    __shared__ u32 pmax[64];
    __shared__ u32 cnt[64];
    __shared__ u16 cand[64 * CAP];

    const int tid = threadIdx.x;
    const int lane = tid & 63;
    const int w = tid >> 6;           // wave 0..7
    const int r0 = blockIdx.x * 64;

    if (tid < 64) { pmax[tid] = 0x007FFFFFu; cnt[tid] = 0; }   // enc(-inf), 0
    // stage xs once: 64 frags of 1KB; wave w stages frags w*8..w*8+7
#pragma unroll
    for (int i = 0; i < 8; ++i) {
        int m = w * 8 + i;
        gl_lds16(xb + (size_t)(blockIdx.x * 64 + m) * 512 + lane * 8, &xs[m * 512]);
    }
    __syncthreads();   // drains vmcnt: xs complete; also publishes pmax/cnt init

    for (int ct = 0; ct < 16; ++ct) {
        const int tbase = ct * 32 + w * 4;    // this wave's 4 code-tiles
        f32x4 acc[4][4] = {};                 // [row-tile][code-tile]
#pragma unroll 4
        for (int kf = 0; kf < 16; ++kf) {
            short8 a[4], b[4];
#pragma unroll
            for (int rt = 0; rt < 4; ++rt)
                a[rt] = *(const short8*)&xs[(rt * 16 + kf) * 512 + lane * 8];
#pragma unroll
            for (int u = 0; u < 4; ++u)
                b[u] = *(const short8*)&cbb[((size_t)(tbase + u) * 16 + kf) * 512 + lane * 8];
#pragma unroll
            for (int rt = 0; rt < 4; ++rt)
#pragma unroll
                for (int u = 0; u < 4; ++u)
                    acc[rt][u] = __builtin_amdgcn_mfma_f32_16x16x32_bf16(a[rt], b[u], acc[rt][u], 0, 0, 0);
        }
        // candidate phase (no barriers; stale pmax reads only over-push)
#pragma unroll
        for (int rt = 0; rt < 4; ++rt)
#pragma unroll
            for (int r = 0; r < 4; ++r) {
                const int rl = rt * 16 + (lane >> 4) * 4 + r;
                float m = fmaxf(fmaxf(acc[rt][0][r], acc[rt][1][r]),
                                fmaxf(acc[rt][2][r], acc[rt][3][r]));
#pragma unroll
                for (int msk = 1; msk < 16; msk <<= 1) m = fmaxf(m, __shfl_xor(m, msk));
                if ((lane & 15) == 0) atomicMax(&pmax[rl], enc_f(m));
                float thr = fmaxf(dec_f(pmax[rl]), m) - DELTA;
#pragma unroll
                for (int u = 0; u < 4; ++u) {
                    if (acc[rt][u][r] >= thr) {
                        u32 p = atomicAdd(&cnt[rl], 1u);
                        int code = (tbase + u) * 16 + (lane & 15);
                        if (p < CAP) cand[rl * CAP + p] = (u16)code;
                    }
                }
            }
    }
    __syncthreads();
    if (tid < 64) cnt_g[r0 + tid] = cnt[tid];
    for (int i = tid; i < 64 * CAP; i += 512) {
        int row = i / CAP, j = i - row * CAP;
        cand_g[(size_t)(r0 + row) * CAP + j] = cand[i];
    }
}

// K4: fp64 rescore of candidates + gather + rotation trick + loss. Wave/row.
// Overflow fallback (rare): parallel per-lane 2-pass exact scan (~60us).
__global__ __launch_bounds__(256) void k4_rotate(const float* __restrict__ x,
                                                 const float* __restrict__ cbn,
                                                 const u16* __restrict__ cand_g,
                                                 const u32* __restrict__ cnt_g,
                                                 float* __restrict__ outq,
                                                 float* __restrict__ out_idx,
                                                 float* __restrict__ lossp) {
    __shared__ float xsh[4 * 512];   // per-wave fallback scratch
    const int row = blockIdx.x * 4 + (threadIdx.x >> 6);
    const int w = threadIdx.x >> 6;
    const int lane = threadIdx.x & 63;
    const float* xp = x + (size_t)row * DIMV + lane * 8;
    float4 a0 = *(const float4*)xp, a1 = *(const float4*)(xp + 4);
    double xd[8] = {a0.x, a0.y, a0.z, a0.w, a1.x, a1.y, a1.z, a1.w};

    u32 nc = cnt_g[row];
    double best = -1e300;
    int bi = CBSZ;
    if (nc <= CAP) {
        for (u32 i = 0; i < nc; ++i) {
            int c = cand_g[(size_t)row * CAP + i];
            const float* cp = cbn + (size_t)c * DIMV + lane * 8;
            float4 c0 = *(const float4*)cp, c1 = *(const float4*)(cp + 4);
            double d = xd[0] * c0.x + xd[1] * c0.y + xd[2] * c0.z + xd[3] * c0.w
                     + xd[4] * c1.x + xd[5] * c1.y + xd[6] * c1.z + xd[7] * c1.w;
#pragma unroll
            for (int m = 1; m < 64; m <<= 1) d += __shfl_xor(d, m);
            if (d > best || (d == best && c < bi)) { best = d; bi = c; }
        }
    } else {
        // exact parallel fallback: stage row, per-lane scan 128 codes
        *(float4*)&xsh[w * 512 + lane * 8] = a0;
        *(float4*)&xsh[w * 512 + lane * 8 + 4] = a1;
        float bf = -1e30f;
        for (int c = lane; c < CBSZ; c += 64) {
            const float* cp = cbn + (size_t)c * DIMV;
            float d = 0.f;
            for (int k = 0; k < DIMV; k += 4) {
                d = fmaf(cp[k],     xsh[w * 512 + k],     d);
                d = fmaf(cp[k + 1], xsh[w * 512 + k + 1], d);
                d = fmaf(cp[k + 2], xsh[w * 512 + k + 2], d);
                d = fmaf(cp[k + 3], xsh[w * 512 + k + 3], d);
            }
            bf = fmaxf(bf, d);
        }
        float M = bf;
#pragma unroll
        for (int m = 1; m < 64; m <<= 1) M = fmaxf(M, __shfl_xor(M, m));
        double bd = -1e300;
        int bc = CBSZ;
        for (int c = lane; c < CBSZ; c += 64) {
            const float* cp = cbn + (size_t)c * DIMV;
            float d = 0.f;
            for (int k = 0; k < DIMV; k += 4) {
                d = fmaf(cp[k],     xsh[w * 512 + k],     d);
                d = fmaf(cp[k + 1], xsh[w * 512 + k + 1], d);
                d = fmaf(cp[k + 2], xsh[w * 512 + k + 2], d);
                d = fmaf(cp[k + 3], xsh[w * 512 + k + 3], d);
            }
            if (d >= M - 0.02f) {
                double dd = 0.0;
                for (int k = 0; k < DIMV; ++k)
                    dd += (double)cp[k] * (double)xsh[w * 512 + k];
                if (dd > bd || (dd == bd && c < bc)) { bd = dd; bc = c; }
            }
        }
#pragma unroll
        for (int m = 1; m < 64; m <<= 1) {
            double ov = __shfl_xor(bd, m);
            int oi = __shfl_xor(bc, m);
            if (ov > bd || (ov == bd && oi < bc)) { bd = ov; bc = oi; }
        }
        bi = bc;
    }
    int ci = bi < 0 ? 0 : (bi > CBSZ - 1 ? CBSZ - 1 : bi);

    float xf[8] = {a0.x, a0.y, a0.z, a0.w, a1.x, a1.y, a1.z, a1.w};
    float ss = 0.f;
#pragma unroll
    for (int i = 0; i < 8; ++i) ss += xf[i] * xf[i];
    ss = wave_sum(ss);
    float nx = fmaxf(sqrtf(ss), 1e-12f);
    float s[8];
#pragma unroll
    for (int i = 0; i < 8; ++i) s[i] = xf[i] / nx;
    const float* tp = cbn + (size_t)ci * DIMV + lane * 8;
    float4 t0 = *(const float4*)tp, t1 = *(const float4*)(tp + 4);
    float t[8] = {t0.x, t0.y, t0.z, t0.w, t1.x, t1.y, t1.z, t1.w};
    float ns2 = 0.f, nt2 = 0.f;
#pragma unroll
    for (int i = 0; i < 8; ++i) { ns2 += s[i] * s[i]; nt2 += t[i] * t[i]; }
    ns2 = wave_sum(ns2); nt2 = wave_sum(nt2);
    float ns = sqrtf(ns2), nt = sqrtf(nt2);
    float ds = fmaxf(ns, 1e-6f), dt = fmaxf(nt, 1e-6f);
    float uu[8], qq[8], wv[8];
#pragma unroll
    for (int i = 0; i < 8; ++i) { uu[i] = s[i] / ds; qq[i] = t[i] / dt; wv[i] = uu[i] + qq[i]; }
    float w2 = 0.f;
#pragma unroll
    for (int i = 0; i < 8; ++i) w2 += wv[i] * wv[i];
    w2 = wave_sum(w2);
    float wn = fmaxf(sqrtf(w2), 1e-12f);
#pragma unroll
    for (int i = 0; i < 8; ++i) wv[i] /= wn;
    float ew = 0.f, eu = 0.f;
#pragma unroll
    for (int i = 0; i < 8; ++i) { ew += s[i] * wv[i]; eu += s[i] * uu[i]; }
    ew = wave_sum(ew); eu = wave_sum(eu);
    const float scale = nt / ds;
    float r[8];
    float lacc = 0.f;
#pragma unroll
    for (int i = 0; i < 8; ++i) {
        r[i] = (s[i] - 2.f * ew * wv[i] + 2.f * eu * qq[i]) * scale;
        float d = s[i] - t[i];
        lacc += d * d;
    }
    float* op = outq + (size_t)row * DIMV + lane * 8;
    *(float4*)op = make_float4(r[0], r[1], r[2], r[3]);
    *(float4*)(op + 4) = make_float4(r[4], r[5], r[6], r[7]);
    lacc = wave_sum(lacc);
    if (lane == 0) {
        out_idx[row] = (float)ci;
        atomicAdd(lossp, lacc);
    }
}

// K5: finalize: 1.25 * sum / (B*N*D)
__global__ void k5_loss(const float* __restrict__ lossp, float* __restrict__ outl) {
    outl[0] = lossp[0] * 1.25f / 16777216.0f;
}

extern "C" void kernel_launch(void* const* d_in, const int* in_sizes, int n_in,
                              void* d_out, int out_size, void* d_ws, size_t ws_size,
                              hipStream_t stream) {
    (void)in_sizes; (void)n_in; (void)out_size; (void)ws_size;
    const float* x  = (const float*)d_in[0];   // (8,4096,512) f32
    const float* W  = (const float*)d_in[1];   // (512,512) f32
    const float* cb = (const float*)d_in[2];   // (8192,512) f32
    float* out = (float*)d_out;
    float* out_q = out;                        // 16,777,216 f32
    float* out_i = out + 16777216;             // 32,768 f32
    float* out_l = out + 16777216 + 32768;     // 1 f32

    // xb scratch lives in the out_q region: written by k0, read by k3,
    // then k4 overwrites out_q with the real output.
    u16* xb = (u16*)d_out;

    float* ws = (float*)d_ws;
    float* cbn = ws;                                  // 4,194,304 f32 (16.8 MB)
    u16*   cbb = (u16*)(cbn + (size_t)CBSZ * DIMV);   // 4,194,304 u16 (8.4 MB)
    u16*   cand_g = cbb + (size_t)CBSZ * DIMV;        // 32768*CAP u16 (3.1 MB)
    u32*   cnt_g = (u32*)(cand_g + (size_t)MROWS * CAP);   // 32,768 u32
    float* lossp = (float*)(cnt_g + MROWS);                // 1 f32

    hipMemsetAsync(lossp, 0, sizeof(float), stream);
    k0_castx<<<MROWS * DIMV / 8 / 256, 256, 0, stream>>>(x, xb);
    k1_implicit<<<dim3(CBSZ / 64, DIMV / 64), 256, 0, stream>>>(cb, W, cbn);
    k2_normrows<<<CBSZ / 4, 256, 0, stream>>>(cbn, cbb);
    k3_scan<<<MROWS / 64, 512, 0, stream>>>(xb, cbb, cand_g, cnt_g);
    k4_rotate<<<MROWS / 4, 256, 0, stream>>>(x, cbn, cand_g, cnt_g, out_q, out_i, lossp);
    k5_loss<<<1, 1, 0, stream>>>(lossp, out_l);
}

// Round 7
// 581.093 us; speedup vs baseline: 8.6833x; 1.6044x over previous
//
#include <hip/hip_runtime.h>

typedef unsigned int u32;
typedef unsigned short u16;
typedef __attribute__((ext_vector_type(8))) short short8;
typedef __attribute__((ext_vector_type(4))) float f32x4;

#define CBSZ 8192
#define DIMV 512
#define MROWS 32768   // 8*4096
#define CAP 48
#define DELTA 0.125f
#define NBLK4 (MROWS / 4)   // 8192 k4 blocks -> loss partials

__device__ __forceinline__ u16 f2bf(float f) {
    u32 u = __float_as_uint(f);
    u32 r = (u + 0x7fffu + ((u >> 16) & 1u)) >> 16;   // RNE
    return (u16)r;
}

__device__ __forceinline__ float wave_sum(float v) {
#pragma unroll
    for (int m = 1; m < 64; m <<= 1) v += __shfl_xor(v, m);
    return v;
}

// monotone float <-> sortable u32
__device__ __forceinline__ u32 enc_f(float f) {
    u32 u = __float_as_uint(f);
    return (u & 0x80000000u) ? ~u : (u | 0x80000000u);
}
__device__ __forceinline__ float dec_f(u32 e) {
    return (e & 0x80000000u) ? __uint_as_float(e & 0x7FFFFFFFu) : __uint_as_float(~e);
}

// async global->LDS, 16B per lane; LDS dest = wave-uniform base + lane*16
__device__ __forceinline__ void gl_lds16(const u16* g, u16* l) {
    __builtin_amdgcn_global_load_lds(
        (const __attribute__((address_space(1))) u32*)g,
        (__attribute__((address_space(3))) u32*)l, 16, 0, 0);
}

// K0: cast x (f32) -> xb (bf16) in MFMA-A-fragment-linear order.
// frag f = R*16 + S (R=row-tile/16, S=k-tile/32); lane L holds row R*16+(L&15),
// k S*32+(L>>4)*8 .. +8, stored as 16B at xb + f*512 + L*8 (u16 elems).
__global__ __launch_bounds__(256) void k0_castx(const float* __restrict__ x,
                                                u16* __restrict__ xb) {
    int t = blockIdx.x * 256 + threadIdx.x;   // 0 .. 2,097,151
    int f = t >> 6;
    int L = t & 63;
    int R = f >> 4, S = f & 15;
    int row = R * 16 + (L & 15);
    int k = S * 32 + (L >> 4) * 8;
    const float* gp = x + (size_t)row * DIMV + k;
    float4 v0 = *(const float4*)gp, v1 = *(const float4*)(gp + 4);
    u32 p0 = (u32)f2bf(v0.x) | ((u32)f2bf(v0.y) << 16);
    u32 p1 = (u32)f2bf(v0.z) | ((u32)f2bf(v0.w) << 16);
    u32 p2 = (u32)f2bf(v1.x) | ((u32)f2bf(v1.y) << 16);
    u32 p3 = (u32)f2bf(v1.z) | ((u32)f2bf(v1.w) << 16);
    *(uint4*)(xb + (size_t)f * 512 + L * 8) = make_uint4(p0, p1, p2, p3);
}

// K1: implicit_cb[c][d] = sum_k cb[c][k] * W[d][k]   (fp32 GEMM, 64x64 tiles)
__global__ __launch_bounds__(256) void k1_implicit(const float* __restrict__ cb,
                                                   const float* __restrict__ W,
                                                   float* __restrict__ outp) {
    __shared__ float As[64 * 64];
    __shared__ float Bs[64 * 64];
    const int c0 = blockIdx.x * 64, d0 = blockIdx.y * 64;
    const int tid = threadIdx.x;
    const int tx = tid & 15, ty = tid >> 4;
    float acc[4][4] = {};
    for (int k0 = 0; k0 < DIMV; k0 += 64) {
        __syncthreads();
#pragma unroll
        for (int it = 0; it < 4; ++it) {
            int chunk = tid + 256 * it;
            int row = chunk >> 4;
            int g = chunk & 15;
            int gs = (g ^ (row & 15)) * 4;
            *(float4*)&As[row * 64 + gs] =
                *(const float4*)(cb + (size_t)(c0 + row) * DIMV + k0 + g * 4);
            *(float4*)&Bs[row * 64 + gs] =
                *(const float4*)(W + (size_t)(d0 + row) * DIMV + k0 + g * 4);
        }
        __syncthreads();
#pragma unroll
        for (int k = 0; k < 64; k += 4) {
            const int g = k >> 2;
            float4 a[4], b[4];
#pragma unroll
            for (int i = 0; i < 4; ++i) a[i] = *(float4*)&As[(ty + 16 * i) * 64 + ((g ^ ty) * 4)];
#pragma unroll
            for (int j = 0; j < 4; ++j) b[j] = *(float4*)&Bs[(tx + 16 * j) * 64 + ((g ^ tx) * 4)];
#pragma unroll
            for (int i = 0; i < 4; ++i)
#pragma unroll
                for (int j = 0; j < 4; ++j) {
                    acc[i][j] = fmaf(a[i].x, b[j].x, acc[i][j]);
                    acc[i][j] = fmaf(a[i].y, b[j].y, acc[i][j]);
                    acc[i][j] = fmaf(a[i].z, b[j].z, acc[i][j]);
                    acc[i][j] = fmaf(a[i].w, b[j].w, acc[i][j]);
                }
        }
    }
#pragma unroll
    for (int i = 0; i < 4; ++i)
#pragma unroll
        for (int j = 0; j < 4; ++j)
            outp[(size_t)(c0 + ty + 16 * i) * DIMV + d0 + tx + 16 * j] = acc[i][j];
}

// K2: in-place row l2norm of cbn + bf16 codebook in B-fragment-linear order.
__global__ __launch_bounds__(256) void k2_normrows(float* __restrict__ cbn,
                                                   u16* __restrict__ cbb) {
    const int row = blockIdx.x * 4 + (threadIdx.x >> 6);
    const int lane = threadIdx.x & 63;
    float* p = cbn + (size_t)row * DIMV + lane * 8;
    float4 v0 = *(float4*)p, v1 = *(float4*)(p + 4);
    float ss = v0.x * v0.x + v0.y * v0.y + v0.z * v0.z + v0.w * v0.w
             + v1.x * v1.x + v1.y * v1.y + v1.z * v1.z + v1.w * v1.w;
    ss = wave_sum(ss);
    float n = fmaxf(sqrtf(ss), 1e-12f);
    v0.x /= n; v0.y /= n; v0.z /= n; v0.w /= n;
    v1.x /= n; v1.y /= n; v1.z /= n; v1.w /= n;
    *(float4*)p = v0;
    *(float4*)(p + 4) = v1;
    u32 p0 = (u32)f2bf(v0.x) | ((u32)f2bf(v0.y) << 16);
    u32 p1 = (u32)f2bf(v0.z) | ((u32)f2bf(v0.w) << 16);
    u32 p2 = (u32)f2bf(v1.x) | ((u32)f2bf(v1.y) << 16);
    u32 p3 = (u32)f2bf(v1.z) | ((u32)f2bf(v1.w) << 16);
    // B-frag-linear: f = (row>>4)*16 + (lane>>2); lane-slot = (lane&3)*16 + (row&15)
    int f = (row >> 4) * 16 + (lane >> 2);
    int Ls = (lane & 3) * 16 + (row & 15);
    *(uint4*)(cbb + (size_t)f * 512 + Ls * 8) = make_uint4(p0, p1, p2, p3);
}

// K3: barrier-free bf16 MFMA prefilter. Grid 512 blocks x 512 thr (8 waves).
// Block = 64 rows (xs resident, 64KB LDS) x all 8192 codes; wave w streams its
// code tiles straight from global (frag-linear cbb) into registers.
// Per-row prefix max in LDS (atomicMax, lag-safe) + candidates within DELTA.
__global__ __launch_bounds__(512, 4) void k3_scan(const u16* __restrict__ xb,
                                                  const u16* __restrict__ cbb,
                                                  u16* __restrict__ cand_g,
                                                  u32* __restrict__ cnt_g) {
    __shared__ __align__(16) u16 xs[64 * 512];   // 64 KB: frag m=rt*16+kf at m*512
    __shared__ u32 pmax[64];
    __shared__ u32 cnt[64];
    __shared__ u16 cand[64 * CAP];

    const int tid = threadIdx.x;
    const int lane = tid & 63;
    const int w = tid >> 6;           // wave 0..7
    const int r0 = blockIdx.x * 64;

    if (tid < 64) { pmax[tid] = 0x007FFFFFu; cnt[tid] = 0; }   // enc(-inf), 0
    // stage xs once: 64 frags of 1KB; wave w stages frags w*8..w*8+7
#pragma unroll
    for (int i = 0; i < 8; ++i) {
        int m = w * 8 + i;
        gl_lds16(xb + (size_t)(blockIdx.x * 64 + m) * 512 + lane * 8, &xs[m * 512]);
    }
    __syncthreads();   // drains vmcnt: xs complete; also publishes pmax/cnt init

    for (int ct = 0; ct < 16; ++ct) {
        const int tbase = ct * 32 + w * 4;    // this wave's 4 code-tiles
        f32x4 acc[4][4] = {};                 // [row-tile][code-tile]
#pragma unroll 4
        for (int kf = 0; kf < 16; ++kf) {
            short8 a[4], b[4];
#pragma unroll
            for (int rt = 0; rt < 4; ++rt)
                a[rt] = *(const short8*)&xs[(rt * 16 + kf) * 512 + lane * 8];
#pragma unroll
            for (int u = 0; u < 4; ++u)
                b[u] = *(const short8*)&cbb[((size_t)(tbase + u) * 16 + kf) * 512 + lane * 8];
#pragma unroll
            for (int rt = 0; rt < 4; ++rt)
#pragma unroll
                for (int u = 0; u < 4; ++u)
                    acc[rt][u] = __builtin_amdgcn_mfma_f32_16x16x32_bf16(a[rt], b[u], acc[rt][u], 0, 0, 0);
        }
        // candidate phase (no barriers; stale pmax reads only over-push)
#pragma unroll
        for (int rt = 0; rt < 4; ++rt)
#pragma unroll
            for (int r = 0; r < 4; ++r) {
                const int rl = rt * 16 + (lane >> 4) * 4 + r;
                float m = fmaxf(fmaxf(acc[rt][0][r], acc[rt][1][r]),
                                fmaxf(acc[rt][2][r], acc[rt][3][r]));
#pragma unroll
                for (int msk = 1; msk < 16; msk <<= 1) m = fmaxf(m, __shfl_xor(m, msk));
                if ((lane & 15) == 0) atomicMax(&pmax[rl], enc_f(m));
                float thr = fmaxf(dec_f(pmax[rl]), m) - DELTA;
#pragma unroll
                for (int u = 0; u < 4; ++u) {
                    if (acc[rt][u][r] >= thr) {
                        u32 p = atomicAdd(&cnt[rl], 1u);
                        int code = (tbase + u) * 16 + (lane & 15);
                        if (p < CAP) cand[rl * CAP + p] = (u16)code;
                    }
                }
            }
    }
    __syncthreads();
    if (tid < 64) cnt_g[r0 + tid] = cnt[tid];
    for (int i = tid; i < 64 * CAP; i += 512) {
        int row = i / CAP, j = i - row * CAP;
        cand_g[(size_t)(r0 + row) * CAP + j] = cand[i];
    }
}

// K4: fp64 rescore of candidates + gather + rotation trick + per-block loss
// partial (NO global atomics). One wave per row, 4 rows per block.
__global__ __launch_bounds__(256) void k4_rotate(const float* __restrict__ x,
                                                 const float* __restrict__ cbn,
                                                 const u16* __restrict__ cand_g,
                                                 const u32* __restrict__ cnt_g,
                                                 float* __restrict__ outq,
                                                 float* __restrict__ out_idx,
                                                 float* __restrict__ lossb) {
    __shared__ float xsh[4 * 512];   // per-wave fallback scratch
    __shared__ float lsum[4];
    const int row = blockIdx.x * 4 + (threadIdx.x >> 6);
    const int w = threadIdx.x >> 6;
    const int lane = threadIdx.x & 63;
    const float* xp = x + (size_t)row * DIMV + lane * 8;
    float4 a0 = *(const float4*)xp, a1 = *(const float4*)(xp + 4);
    double xd[8] = {a0.x, a0.y, a0.z, a0.w, a1.x, a1.y, a1.z, a1.w};

    u32 nc = cnt_g[row];
    double best = -1e300;
    int bi = CBSZ;
    if (nc <= CAP) {
        u32 i = 0;
        for (; i + 2 <= nc; i += 2) {        // 2-way ILP: interleaved reductions
            int ca = cand_g[(size_t)row * CAP + i];
            int cb2 = cand_g[(size_t)row * CAP + i + 1];
            const float* pa = cbn + (size_t)ca * DIMV + lane * 8;
            const float* pb = cbn + (size_t)cb2 * DIMV + lane * 8;
            float4 a0v = *(const float4*)pa, a1v = *(const float4*)(pa + 4);
            float4 b0v = *(const float4*)pb, b1v = *(const float4*)(pb + 4);
            double da = xd[0] * a0v.x + xd[1] * a0v.y + xd[2] * a0v.z + xd[3] * a0v.w
                      + xd[4] * a1v.x + xd[5] * a1v.y + xd[6] * a1v.z + xd[7] * a1v.w;
            double db = xd[0] * b0v.x + xd[1] * b0v.y + xd[2] * b0v.z + xd[3] * b0v.w
                      + xd[4] * b1v.x + xd[5] * b1v.y + xd[6] * b1v.z + xd[7] * b1v.w;
#pragma unroll
            for (int m = 1; m < 64; m <<= 1) {
                da += __shfl_xor(da, m);
                db += __shfl_xor(db, m);
            }
            if (da > best || (da == best && ca < bi)) { best = da; bi = ca; }
            if (db > best || (db == best && cb2 < bi)) { best = db; bi = cb2; }
        }
        if (i < nc) {
            int c = cand_g[(size_t)row * CAP + i];
            const float* cp = cbn + (size_t)c * DIMV + lane * 8;
            float4 c0 = *(const float4*)cp, c1 = *(const float4*)(cp + 4);
            double d = xd[0] * c0.x + xd[1] * c0.y + xd[2] * c0.z + xd[3] * c0.w
                     + xd[4] * c1.x + xd[5] * c1.y + xd[6] * c1.z + xd[7] * c1.w;
#pragma unroll
            for (int m = 1; m < 64; m <<= 1) d += __shfl_xor(d, m);
            if (d > best || (d == best && c < bi)) { best = d; bi = c; }
        }
    } else {
        // exact parallel fallback (statistically never): per-lane 2-pass scan
        *(float4*)&xsh[w * 512 + lane * 8] = a0;
        *(float4*)&xsh[w * 512 + lane * 8 + 4] = a1;
        float bf = -1e30f;
        for (int c = lane; c < CBSZ; c += 64) {
            const float* cp = cbn + (size_t)c * DIMV;
            float d = 0.f;
            for (int k = 0; k < DIMV; k += 4) {
                d = fmaf(cp[k],     xsh[w * 512 + k],     d);
                d = fmaf(cp[k + 1], xsh[w * 512 + k + 1], d);
                d = fmaf(cp[k + 2], xsh[w * 512 + k + 2], d);
                d = fmaf(cp[k + 3], xsh[w * 512 + k + 3], d);
            }
            bf = fmaxf(bf, d);
        }
        float M = bf;
#pragma unroll
        for (int m = 1; m < 64; m <<= 1) M = fmaxf(M, __shfl_xor(M, m));
        double bd = -1e300;
        int bc = CBSZ;
        for (int c = lane; c < CBSZ; c += 64) {
            const float* cp = cbn + (size_t)c * DIMV;
            float d = 0.f;
            for (int k = 0; k < DIMV; k += 4) {
                d = fmaf(cp[k],     xsh[w * 512 + k],     d);
                d = fmaf(cp[k + 1], xsh[w * 512 + k + 1], d);
                d = fmaf(cp[k + 2], xsh[w * 512 + k + 2], d);
                d = fmaf(cp[k + 3], xsh[w * 512 + k + 3], d);
            }
            if (d >= M - 0.02f) {
                double dd = 0.0;
                for (int k = 0; k < DIMV; ++k)
                    dd += (double)cp[k] * (double)xsh[w * 512 + k];
                if (dd > bd || (dd == bd && c < bc)) { bd = dd; bc = c; }
            }
        }
#pragma unroll
        for (int m = 1; m < 64; m <<= 1) {
            double ov = __shfl_xor(bd, m);
            int oi = __shfl_xor(bc, m);
            if (ov > bd || (ov == bd && oi < bc)) { bd = ov; bc = oi; }
        }
        bi = bc;
    }
    int ci = bi < 0 ? 0 : (bi > CBSZ - 1 ? CBSZ - 1 : bi);

    float xf[8] = {a0.x, a0.y, a0.z, a0.w, a1.x, a1.y, a1.z, a1.w};
    float ss = 0.f;
#pragma unroll
    for (int i = 0; i < 8; ++i) ss += xf[i] * xf[i];
    ss = wave_sum(ss);
    float nx = fmaxf(sqrtf(ss), 1e-12f);
    float s[8];
#pragma unroll
    for (int i = 0; i < 8; ++i) s[i] = xf[i] / nx;
    const float* tp = cbn + (size_t)ci * DIMV + lane * 8;
    float4 t0 = *(const float4*)tp, t1 = *(const float4*)(tp + 4);
    float t[8] = {t0.x, t0.y, t0.z, t0.w, t1.x, t1.y, t1.z, t1.w};
    float ns2 = 0.f, nt2 = 0.f;
#pragma unroll
    for (int i = 0; i < 8; ++i) { ns2 += s[i] * s[i]; nt2 += t[i] * t[i]; }
    ns2 = wave_sum(ns2); nt2 = wave_sum(nt2);
    float ns = sqrtf(ns2), nt = sqrtf(nt2);
    float ds = fmaxf(ns, 1e-6f), dt = fmaxf(nt, 1e-6f);
    float uu[8], qq[8], wv[8];
#pragma unroll
    for (int i = 0; i < 8; ++i) { uu[i] = s[i] / ds; qq[i] = t[i] / dt; wv[i] = uu[i] + qq[i]; }
    float w2 = 0.f;
#pragma unroll
    for (int i = 0; i < 8; ++i) w2 += wv[i] * wv[i];
    w2 = wave_sum(w2);
    float wn = fmaxf(sqrtf(w2), 1e-12f);
#pragma unroll
    for (int i = 0; i < 8; ++i) wv[i] /= wn;
    float ew = 0.f, eu = 0.f;
#pragma unroll
    for (int i = 0; i < 8; ++i) { ew += s[i] * wv[i]; eu += s[i] * uu[i]; }
    ew = wave_sum(ew); eu = wave_sum(eu);
    const float scale = nt / ds;
    float r[8];
    float lacc = 0.f;
#pragma unroll
    for (int i = 0; i < 8; ++i) {
        r[i] = (s[i] - 2.f * ew * wv[i] + 2.f * eu * qq[i]) * scale;
        float d = s[i] - t[i];
        lacc += d * d;
    }
    float* op = outq + (size_t)row * DIMV + lane * 8;
    *(float4*)op = make_float4(r[0], r[1], r[2], r[3]);
    *(float4*)(op + 4) = make_float4(r[4], r[5], r[6], r[7]);
    lacc = wave_sum(lacc);
    if (lane == 0) {
        out_idx[row] = (float)ci;
        lsum[w] = lacc;
    }
    __syncthreads();
    if (threadIdx.x == 0)
        lossb[blockIdx.x] = lsum[0] + lsum[1] + lsum[2] + lsum[3];
}

// K5: reduce 8192 per-block partials deterministically; 1.25 * sum / (B*N*D)
__global__ __launch_bounds__(256) void k5_loss(const float* __restrict__ lossb,
                                               float* __restrict__ outl) {
    __shared__ float wsum[4];
    const int tid = threadIdx.x;
    float s = 0.f;
    for (int i = tid; i < NBLK4; i += 256) s += lossb[i];
    s = wave_sum(s);
    if ((tid & 63) == 0) wsum[tid >> 6] = s;
    __syncthreads();
    if (tid == 0)
        outl[0] = (wsum[0] + wsum[1] + wsum[2] + wsum[3]) * 1.25f / 16777216.0f;
}

extern "C" void kernel_launch(void* const* d_in, const int* in_sizes, int n_in,
                              void* d_out, int out_size, void* d_ws, size_t ws_size,
                              hipStream_t stream) {
    (void)in_sizes; (void)n_in; (void)out_size; (void)ws_size;
    const float* x  = (const float*)d_in[0];   // (8,4096,512) f32
    const float* W  = (const float*)d_in[1];   // (512,512) f32
    const float* cb = (const float*)d_in[2];   // (8192,512) f32
    float* out = (float*)d_out;
    float* out_q = out;                        // 16,777,216 f32
    float* out_i = out + 16777216;             // 32,768 f32
    float* out_l = out + 16777216 + 32768;     // 1 f32

    // xb scratch lives in the out_q region: written by k0, read by k3,
    // then k4 overwrites out_q with the real output.
    u16* xb = (u16*)d_out;

    float* ws = (float*)d_ws;
    float* cbn = ws;                                  // 4,194,304 f32 (16.8 MB)
    u16*   cbb = (u16*)(cbn + (size_t)CBSZ * DIMV);   // 4,194,304 u16 (8.4 MB)
    u16*   cand_g = cbb + (size_t)CBSZ * DIMV;        // 32768*CAP u16 (3.1 MB)
    u32*   cnt_g = (u32*)(cand_g + (size_t)MROWS * CAP);   // 32,768 u32
    float* lossb = (float*)(cnt_g + MROWS);                // 8192 f32

    k0_castx<<<MROWS * DIMV / 8 / 256, 256, 0, stream>>>(x, xb);
    k1_implicit<<<dim3(CBSZ / 64, DIMV / 64), 256, 0, stream>>>(cb, W, cbn);
    k2_normrows<<<CBSZ / 4, 256, 0, stream>>>(cbn, cbb);
    k3_scan<<<MROWS / 64, 512, 0, stream>>>(xb, cbb, cand_g, cnt_g);
    k4_rotate<<<MROWS / 4, 256, 0, stream>>>(x, cbn, cand_g, cnt_g, out_q, out_i, lossb);
    k5_loss<<<1, 256, 0, stream>>>(lossb, out_l);
}